// Round 1
// baseline (32123.456 us; speedup 1.0000x reference)
//
#include <hip/hip_runtime.h>

typedef __bf16 bf16x8 __attribute__((ext_vector_type(8)));
typedef float f32x4 __attribute__((ext_vector_type(4)));

#define T_STEPS 512

__device__ __forceinline__ float fsig(float v) { return 1.0f / (1.0f + __expf(-v)); }
__device__ __forceinline__ float ftanhf(float v) {
    float a = fminf(fmaxf(v, -15.0f), 15.0f);
    float e = __expf(2.0f * a);
    return (e - 1.0f) / (e + 1.0f);
}
__device__ __forceinline__ unsigned short f2bfu(float f) {
    unsigned u = __float_as_uint(f);
    u += 0x7fffu + ((u >> 16) & 1u);
    return (unsigned short)(u >> 16);
}
__device__ __forceinline__ bf16x8 cvt8(float4 a, float4 b) {
    bf16x8 f;
    f[0] = (__bf16)a.x; f[1] = (__bf16)a.y; f[2] = (__bf16)a.z; f[3] = (__bf16)a.w;
    f[4] = (__bf16)b.x; f[5] = (__bf16)b.y; f[6] = (__bf16)b.z; f[7] = (__bf16)b.w;
    return f;
}

// Persistent LSTM: 256 blocks (1/CU) x 512 threads (8 waves).
// Block (bg,cg): bg = batch group (16 rows), cg = h-col group (16 cols x 4 gates).
// Wave w holds Wcat fragments for K-chunk [w*256,(w+1)*256) in 128 VGPRs for the
// whole kernel; waves 0-3 are the x-half (K<1024), waves 4-7 the h-half.
__global__ __launch_bounds__(512, 2) void lstm_persist(
    const float* __restrict__ x, const float* __restrict__ h0,
    const float* __restrict__ c0, const float* __restrict__ w_ih,
    const float* __restrict__ w_hh, const float* __restrict__ b_ih,
    const float* __restrict__ b_hh, float* __restrict__ out,
    unsigned short* __restrict__ hb, int* __restrict__ arrive)
{
    const int tid  = threadIdx.x;
    const int wave = tid >> 6;
    const int lane = tid & 63;
    const int bid  = blockIdx.x;
    const int bg   = bid >> 6;   // 0..3
    const int cg   = bid & 63;   // 0..63
    const int colbase = cg << 4;
    const int batbase = bg << 4;

    __shared__ float red[8][4][4][64];  // [wave][gate][reg][lane] = 32 KB

    const int quad = lane >> 4;
    const int l15  = lane & 15;

    // ---------- one-time weight preload into registers (bf16) ----------
    // B-operand layout for mfma_f32_16x16x32_bf16: lane holds B[k=quad*8+j][n=lane&15],
    // i.e. load W (row-major [gatecol][k]) exactly like an A fragment.
    bf16x8 bw[8][4];
    {
        const float* wsrc = (wave < 4) ? w_ih : w_hh;
        const int koff = (wave & 3) * 256 + quad * 8;
        #pragma unroll
        for (int n = 0; n < 4; ++n) {
            const float* prow = wsrc + (size_t)((n << 10) + colbase + l15) * 1024 + koff;
            #pragma unroll
            for (int kk = 0; kk < 8; ++kk) {
                float4 a = *(const float4*)(prow + kk * 32);
                float4 b = *(const float4*)(prow + kk * 32 + 4);
                bw[kk][n] = cvt8(a, b);
            }
        }
    }

    // ---------- per-cell persistent state (threads 0..255) ----------
    // Cell (row,col): row = (cl>>4)*4 + cv, col = cl&15  (matches MFMA C/D layout).
    float creg = 0.0f, bias0 = 0.f, bias1 = 0.f, bias2 = 0.f, bias3 = 0.f;
    int cellcolg = 0, cellb = 0;
    if (tid < 256) {
        const int cl = tid & 63;
        const int cv = tid >> 6;
        const int cellrow = ((cl >> 4) << 2) + cv;
        cellcolg = colbase + (cl & 15);
        cellb    = batbase + cellrow;
        creg  = c0[cellb * 1024 + cellcolg];
        bias0 = b_ih[cellcolg]        + b_hh[cellcolg];
        bias1 = b_ih[1024 + cellcolg] + b_hh[1024 + cellcolg];
        bias2 = b_ih[2048 + cellcolg] + b_hh[2048 + cellcolg];
        bias3 = b_ih[3072 + cellcolg] + b_hh[3072 + cellcolg];
    }

    float* outp = out;
    float* hnp  = out + (size_t)64 * 512 * 1024;
    float* cnp  = hnp + 64 * 1024;

    const int abatch = batbase + l15;   // A-operand row = batch

    for (int t = 0; t < T_STEPS; ++t) {
        f32x4 acc[4];
        #pragma unroll
        for (int n = 0; n < 4; ++n) acc[n] = (f32x4){0.f, 0.f, 0.f, 0.f};

        if (wave < 4) {
            // x_t contribution (K in [wave*256, wave*256+256))
            const float* px = x + ((size_t)abatch * 512 + t) * 1024 + wave * 256 + quad * 8;
            #pragma unroll
            for (int kk = 0; kk < 8; ++kk) {
                float4 a = *(const float4*)(px + kk * 32);
                float4 b = *(const float4*)(px + kk * 32 + 4);
                bf16x8 af = cvt8(a, b);
                acc[0] = __builtin_amdgcn_mfma_f32_16x16x32_bf16(af, bw[kk][0], acc[0], 0, 0, 0);
                acc[1] = __builtin_amdgcn_mfma_f32_16x16x32_bf16(af, bw[kk][1], acc[1], 0, 0, 0);
                acc[2] = __builtin_amdgcn_mfma_f32_16x16x32_bf16(af, bw[kk][2], acc[2], 0, 0, 0);
                acc[3] = __builtin_amdgcn_mfma_f32_16x16x32_bf16(af, bw[kk][3], acc[3], 0, 0, 0);
            }
        } else if (t == 0) {
            const float* ph = h0 + abatch * 1024 + (wave & 3) * 256 + quad * 8;
            #pragma unroll
            for (int kk = 0; kk < 8; ++kk) {
                float4 a = *(const float4*)(ph + kk * 32);
                float4 b = *(const float4*)(ph + kk * 32 + 4);
                bf16x8 af = cvt8(a, b);
                acc[0] = __builtin_amdgcn_mfma_f32_16x16x32_bf16(af, bw[kk][0], acc[0], 0, 0, 0);
                acc[1] = __builtin_amdgcn_mfma_f32_16x16x32_bf16(af, bw[kk][1], acc[1], 0, 0, 0);
                acc[2] = __builtin_amdgcn_mfma_f32_16x16x32_bf16(af, bw[kk][2], acc[2], 0, 0, 0);
                acc[3] = __builtin_amdgcn_mfma_f32_16x16x32_bf16(af, bw[kk][3], acc[3], 0, 0, 0);
            }
        } else {
            const unsigned short* ph = hb + ((t - 1) & 1) * 65536
                                         + abatch * 1024 + (wave & 3) * 256 + quad * 8;
            #pragma unroll
            for (int kk = 0; kk < 8; ++kk) {
                union { uint4 u; bf16x8 v; } cc;
                cc.u = *(const uint4*)(ph + kk * 32);
                bf16x8 af = cc.v;
                acc[0] = __builtin_amdgcn_mfma_f32_16x16x32_bf16(af, bw[kk][0], acc[0], 0, 0, 0);
                acc[1] = __builtin_amdgcn_mfma_f32_16x16x32_bf16(af, bw[kk][1], acc[1], 0, 0, 0);
                acc[2] = __builtin_amdgcn_mfma_f32_16x16x32_bf16(af, bw[kk][2], acc[2], 0, 0, 0);
                acc[3] = __builtin_amdgcn_mfma_f32_16x16x32_bf16(af, bw[kk][3], acc[3], 0, 0, 0);
            }
        }

        // K-partial sums -> LDS (stride-1 across lanes: conflict-free)
        #pragma unroll
        for (int n = 0; n < 4; ++n) {
            #pragma unroll
            for (int v = 0; v < 4; ++v)
                red[wave][n][v][lane] = acc[n][v];
        }
        __syncthreads();

        if (tid < 256) {
            const int cl = tid & 63;
            const int cv = tid >> 6;
            float g0 = bias0, g1 = bias1, g2 = bias2, g3 = bias3;
            #pragma unroll
            for (int w = 0; w < 8; ++w) {
                g0 += red[w][0][cv][cl];
                g1 += red[w][1][cv][cl];
                g2 += red[w][2][cv][cl];
                g3 += red[w][3][cv][cl];
            }
            float ig = fsig(g0), fg = fsig(g1), gg = ftanhf(g2), og = fsig(g3);
            creg = fg * creg + ig * gg;
            float h = og * ftanhf(creg);
            outp[((size_t)cellb * 512 + t) * 1024 + cellcolg] = h;
            hb[(t & 1) * 65536 + cellb * 1024 + cellcolg] = f2bfu(h);
            if (t == T_STEPS - 1) {
                hnp[cellb * 1024 + cellcolg] = h;
                cnp[cellb * 1024 + cellcolg] = creg;
            }
        }

        if (t < T_STEPS - 1) {
            // release: drain each wave's stores (wbL2) before signalling
            __threadfence();
            __syncthreads();
            if (tid == 0)
                __hip_atomic_store(&arrive[bid], t + 1, __ATOMIC_RELEASE,
                                   __HIP_MEMORY_SCOPE_AGENT);
            if (tid < 256) {
                // ws poison 0xAAAAAAAA is negative as int -> no init needed
                while (__hip_atomic_load(&arrive[tid], __ATOMIC_RELAXED,
                                         __HIP_MEMORY_SCOPE_AGENT) < t + 1) {
                    __builtin_amdgcn_s_sleep(2);
                }
            }
            __syncthreads();
            // acquire: invalidate caches so next step's hb reads are fresh
            __builtin_amdgcn_fence(__ATOMIC_ACQUIRE, "agent");
        }
    }
}

extern "C" void kernel_launch(void* const* d_in, const int* in_sizes, int n_in,
                              void* d_out, int out_size, void* d_ws, size_t ws_size,
                              hipStream_t stream) {
    const float* x   = (const float*)d_in[0];
    const float* h0  = (const float*)d_in[1];
    const float* c0  = (const float*)d_in[2];
    const float* wih = (const float*)d_in[3];
    const float* whh = (const float*)d_in[4];
    const float* bih = (const float*)d_in[5];
    const float* bhh = (const float*)d_in[6];
    float* out = (float*)d_out;
    // ws layout: hb[2][64][1024] bf16 (256 KB) | arrive[256] int (1 KB)
    unsigned short* hb = (unsigned short*)d_ws;
    int* arrive = (int*)((char*)d_ws + 2 * 65536 * sizeof(unsigned short));
    hipLaunchKernelGGL(lstm_persist, dim3(256), dim3(512), 0, stream,
                       x, h0, c0, wih, whh, bih, bhh, out, hb, arrive);
}

// Round 2
// 5324.248 us; speedup vs baseline: 6.0334x; 6.0334x over previous
//
#include <hip/hip_runtime.h>

typedef __bf16 bf16x8 __attribute__((ext_vector_type(8)));
typedef float f32x4 __attribute__((ext_vector_type(4)));

#define T_STEPS 512

__device__ __forceinline__ float fsig(float v) { return 1.0f / (1.0f + __expf(-v)); }
__device__ __forceinline__ float ftanhf(float v) {
    float a = fminf(fmaxf(v, -15.0f), 15.0f);
    float e = __expf(2.0f * a);
    return (e - 1.0f) / (e + 1.0f);
}
__device__ __forceinline__ unsigned short f2bfu(float f) {
    unsigned u = __float_as_uint(f);
    u += 0x7fffu + ((u >> 16) & 1u);
    return (unsigned short)(u >> 16);
}
__device__ __forceinline__ bf16x8 cvt8(float4 a, float4 b) {
    bf16x8 f;
    f[0] = (__bf16)a.x; f[1] = (__bf16)a.y; f[2] = (__bf16)a.z; f[3] = (__bf16)a.w;
    f[4] = (__bf16)b.x; f[5] = (__bf16)b.y; f[6] = (__bf16)b.z; f[7] = (__bf16)b.w;
    return f;
}

// Coherent (cross-XCD) access helpers: per-access LLC coherence, NO cache-sweep
// fences. sc0 sc1 on loads = forced miss past L1/L2 (read LLC); on stores =
// write-through to LLC (no dirty L2 line to write back later).
__device__ __forceinline__ void load_hb8(const unsigned short* p, uint4* f) {
    asm volatile(
        "global_load_dwordx4 %0, %8, off sc0 sc1\n\t"
        "global_load_dwordx4 %1, %8, off offset:64 sc0 sc1\n\t"
        "global_load_dwordx4 %2, %8, off offset:128 sc0 sc1\n\t"
        "global_load_dwordx4 %3, %8, off offset:192 sc0 sc1\n\t"
        "global_load_dwordx4 %4, %8, off offset:256 sc0 sc1\n\t"
        "global_load_dwordx4 %5, %8, off offset:320 sc0 sc1\n\t"
        "global_load_dwordx4 %6, %8, off offset:384 sc0 sc1\n\t"
        "global_load_dwordx4 %7, %8, off offset:448 sc0 sc1\n\t"
        "s_waitcnt vmcnt(0)"
        : "=&v"(f[0]), "=&v"(f[1]), "=&v"(f[2]), "=&v"(f[3]),
          "=&v"(f[4]), "=&v"(f[5]), "=&v"(f[6]), "=&v"(f[7])
        : "v"(p)
        : "memory");
}
__device__ __forceinline__ void store_hb(unsigned short* p, unsigned short v) {
    unsigned int vv = v;
    asm volatile("global_store_short %0, %1, off sc0 sc1"
                 :: "v"(p), "v"(vv) : "memory");
}
__device__ __forceinline__ void vm_drain() {
    asm volatile("s_waitcnt vmcnt(0)" ::: "memory");
}

// Persistent LSTM: 256 blocks (1/CU) x 512 threads (8 waves).
// Block (bg,cg): bg = batch group (16 rows), cg = h-col group (16 cols x 4 gates).
// Wave w holds Wcat fragments for K-chunk [w*256,(w+1)*256) in 128 regs (AGPR-able)
// for the whole kernel; waves 0-3 are the x-half (K<1024), waves 4-7 the h-half.
// Barrier: 4 independent 64-block barriers (one per bg) — block (bg,cg) only
// consumes h rows of its own batch group.
__global__ __launch_bounds__(512, 2) void lstm_persist(
    const float* __restrict__ x, const float* __restrict__ h0,
    const float* __restrict__ c0, const float* __restrict__ w_ih,
    const float* __restrict__ w_hh, const float* __restrict__ b_ih,
    const float* __restrict__ b_hh, float* __restrict__ out,
    unsigned short* __restrict__ hb, int* __restrict__ arrive)
{
    const int tid  = threadIdx.x;
    const int wave = tid >> 6;
    const int lane = tid & 63;
    const int bid  = blockIdx.x;
    const int bg   = bid >> 6;   // 0..3
    const int cg   = bid & 63;   // 0..63
    const int colbase = cg << 4;
    const int batbase = bg << 4;

    __shared__ float red[8][4][4][64];  // [wave][gate][reg][lane] = 32 KB

    const int quad = lane >> 4;
    const int l15  = lane & 15;

    // ---------- one-time weight preload into registers (bf16) ----------
    bf16x8 bw[8][4];
    {
        const float* wsrc = (wave < 4) ? w_ih : w_hh;
        const int koff = (wave & 3) * 256 + quad * 8;
        #pragma unroll
        for (int n = 0; n < 4; ++n) {
            const float* prow = wsrc + (size_t)((n << 10) + colbase + l15) * 1024 + koff;
            #pragma unroll
            for (int kk = 0; kk < 8; ++kk) {
                float4 a = *(const float4*)(prow + kk * 32);
                float4 b = *(const float4*)(prow + kk * 32 + 4);
                bw[kk][n] = cvt8(a, b);
            }
        }
    }

    // ---------- per-cell persistent state (threads 0..255) ----------
    float creg = 0.0f, bias0 = 0.f, bias1 = 0.f, bias2 = 0.f, bias3 = 0.f;
    int cellcolg = 0, cellb = 0;
    if (tid < 256) {
        const int cl = tid & 63;
        const int cv = tid >> 6;
        const int cellrow = ((cl >> 4) << 2) + cv;
        cellcolg = colbase + (cl & 15);
        cellb    = batbase + cellrow;
        creg  = c0[cellb * 1024 + cellcolg];
        bias0 = b_ih[cellcolg]        + b_hh[cellcolg];
        bias1 = b_ih[1024 + cellcolg] + b_hh[1024 + cellcolg];
        bias2 = b_ih[2048 + cellcolg] + b_hh[2048 + cellcolg];
        bias3 = b_ih[3072 + cellcolg] + b_hh[3072 + cellcolg];
    }

    float* outp = out;
    float* hnp  = out + (size_t)64 * 512 * 1024;
    float* cnp  = hnp + 64 * 1024;

    const int abatch = batbase + l15;   // A-operand row = batch

    for (int t = 0; t < T_STEPS; ++t) {
        f32x4 acc[4];
        #pragma unroll
        for (int n = 0; n < 4; ++n) acc[n] = (f32x4){0.f, 0.f, 0.f, 0.f};

        if (wave < 4) {
            // x_t contribution (plain cached loads — x is read-only, L2 stays warm)
            const float* px = x + ((size_t)abatch * 512 + t) * 1024 + wave * 256 + quad * 8;
            #pragma unroll
            for (int kk = 0; kk < 8; ++kk) {
                float4 a = *(const float4*)(px + kk * 32);
                float4 b = *(const float4*)(px + kk * 32 + 4);
                bf16x8 af = cvt8(a, b);
                acc[0] = __builtin_amdgcn_mfma_f32_16x16x32_bf16(af, bw[kk][0], acc[0], 0, 0, 0);
                acc[1] = __builtin_amdgcn_mfma_f32_16x16x32_bf16(af, bw[kk][1], acc[1], 0, 0, 0);
                acc[2] = __builtin_amdgcn_mfma_f32_16x16x32_bf16(af, bw[kk][2], acc[2], 0, 0, 0);
                acc[3] = __builtin_amdgcn_mfma_f32_16x16x32_bf16(af, bw[kk][3], acc[3], 0, 0, 0);
            }
        } else if (t == 0) {
            const float* ph = h0 + abatch * 1024 + (wave & 3) * 256 + quad * 8;
            #pragma unroll
            for (int kk = 0; kk < 8; ++kk) {
                float4 a = *(const float4*)(ph + kk * 32);
                float4 b = *(const float4*)(ph + kk * 32 + 4);
                bf16x8 af = cvt8(a, b);
                acc[0] = __builtin_amdgcn_mfma_f32_16x16x32_bf16(af, bw[kk][0], acc[0], 0, 0, 0);
                acc[1] = __builtin_amdgcn_mfma_f32_16x16x32_bf16(af, bw[kk][1], acc[1], 0, 0, 0);
                acc[2] = __builtin_amdgcn_mfma_f32_16x16x32_bf16(af, bw[kk][2], acc[2], 0, 0, 0);
                acc[3] = __builtin_amdgcn_mfma_f32_16x16x32_bf16(af, bw[kk][3], acc[3], 0, 0, 0);
            }
        } else {
            const unsigned short* ph = hb + ((t - 1) & 1) * 65536
                                         + abatch * 1024 + (wave & 3) * 256 + quad * 8;
            uint4 fr[8];
            load_hb8(ph, fr);
            #pragma unroll
            for (int kk = 0; kk < 8; ++kk) {
                union { uint4 u; bf16x8 v; } cc;
                cc.u = fr[kk];
                bf16x8 af = cc.v;
                acc[0] = __builtin_amdgcn_mfma_f32_16x16x32_bf16(af, bw[kk][0], acc[0], 0, 0, 0);
                acc[1] = __builtin_amdgcn_mfma_f32_16x16x32_bf16(af, bw[kk][1], acc[1], 0, 0, 0);
                acc[2] = __builtin_amdgcn_mfma_f32_16x16x32_bf16(af, bw[kk][2], acc[2], 0, 0, 0);
                acc[3] = __builtin_amdgcn_mfma_f32_16x16x32_bf16(af, bw[kk][3], acc[3], 0, 0, 0);
            }
        }

        // K-partial sums -> LDS (stride-1 across lanes: conflict-free)
        #pragma unroll
        for (int n = 0; n < 4; ++n) {
            #pragma unroll
            for (int v = 0; v < 4; ++v)
                red[wave][n][v][lane] = acc[n][v];
        }
        __syncthreads();

        if (tid < 256) {
            const int cl = tid & 63;
            const int cv = tid >> 6;
            float g0 = bias0, g1 = bias1, g2 = bias2, g3 = bias3;
            #pragma unroll
            for (int w = 0; w < 8; ++w) {
                g0 += red[w][0][cv][cl];
                g1 += red[w][1][cv][cl];
                g2 += red[w][2][cv][cl];
                g3 += red[w][3][cv][cl];
            }
            float ig = fsig(g0), fg = fsig(g1), gg = ftanhf(g2), og = fsig(g3);
            creg = fg * creg + ig * gg;
            float h = og * ftanhf(creg);
            outp[((size_t)cellb * 512 + t) * 1024 + cellcolg] = h;
            // coherent write-through of h for the next step's consumers
            store_hb(hb + (t & 1) * 65536 + cellb * 1024 + cellcolg, f2bfu(h));
            if (t == T_STEPS - 1) {
                hnp[cellb * 1024 + cellcolg] = h;
                cnp[cellb * 1024 + cellcolg] = creg;
            }
        }

        if (t < T_STEPS - 1) {
            // release: drain this wave's stores to the coherence point (no wbL2!)
            vm_drain();
            __syncthreads();
            if (tid == 0)
                __hip_atomic_store(&arrive[bid], t + 1, __ATOMIC_RELAXED,
                                   __HIP_MEMORY_SCOPE_AGENT);
            // per-bg barrier: wait only for the 64 blocks of our batch group
            if (tid < 64) {
                const int* slot = &arrive[(bg << 6) + tid];
                // ws poison 0xAAAAAAAA is negative as int -> no init needed
                while (__hip_atomic_load(slot, __ATOMIC_RELAXED,
                                         __HIP_MEMORY_SCOPE_AGENT) < t + 1) {
                    __builtin_amdgcn_s_sleep(1);
                }
            }
            __syncthreads();
            // NO acquire cache-sweep: next step's hb loads bypass L1/L2 (sc0 sc1)
        }
    }
}

extern "C" void kernel_launch(void* const* d_in, const int* in_sizes, int n_in,
                              void* d_out, int out_size, void* d_ws, size_t ws_size,
                              hipStream_t stream) {
    const float* x   = (const float*)d_in[0];
    const float* h0  = (const float*)d_in[1];
    const float* c0  = (const float*)d_in[2];
    const float* wih = (const float*)d_in[3];
    const float* whh = (const float*)d_in[4];
    const float* bih = (const float*)d_in[5];
    const float* bhh = (const float*)d_in[6];
    float* out = (float*)d_out;
    // ws layout: hb[2][64][1024] bf16 (256 KB) | arrive[256] int (1 KB)
    unsigned short* hb = (unsigned short*)d_ws;
    int* arrive = (int*)((char*)d_ws + 2 * 65536 * sizeof(unsigned short));
    hipLaunchKernelGGL(lstm_persist, dim3(256), dim3(512), 0, stream,
                       x, h0, c0, wih, whh, bih, bhh, out, hb, arrive);
}

// Round 3
// 4146.102 us; speedup vs baseline: 7.7479x; 1.2842x over previous
//
#include <hip/hip_runtime.h>

typedef __bf16 bf16x8 __attribute__((ext_vector_type(8)));
typedef float f32x4 __attribute__((ext_vector_type(4)));

#define T_STEPS 512

__device__ __forceinline__ float fsig(float v) { return 1.0f / (1.0f + __expf(-v)); }
__device__ __forceinline__ float ftanhf(float v) {
    float a = fminf(fmaxf(v, -15.0f), 15.0f);
    float e = __expf(2.0f * a);
    return (e - 1.0f) / (e + 1.0f);
}
__device__ __forceinline__ unsigned short f2bfu(float f) {
    unsigned u = __float_as_uint(f);
    u += 0x7fffu + ((u >> 16) & 1u);
    return (unsigned short)(u >> 16);
}
__device__ __forceinline__ bf16x8 cvt8(float4 a, float4 b) {
    bf16x8 f;
    f[0] = (__bf16)a.x; f[1] = (__bf16)a.y; f[2] = (__bf16)a.z; f[3] = (__bf16)a.w;
    f[4] = (__bf16)b.x; f[5] = (__bf16)b.y; f[6] = (__bf16)b.z; f[7] = (__bf16)b.w;
    return f;
}

// Coherent (cross-XCD) access helpers: per-access LLC coherence, NO cache-sweep
// fences. sc0 sc1 on loads = forced miss past L1/L2 (read the LLC coherence
// point); on stores = write-through (no dirty L2 line left behind).
__device__ __forceinline__ void load_hb8(const unsigned short* p, uint4* f) {
    asm volatile(
        "global_load_dwordx4 %0, %8, off sc0 sc1\n\t"
        "global_load_dwordx4 %1, %8, off offset:64 sc0 sc1\n\t"
        "global_load_dwordx4 %2, %8, off offset:128 sc0 sc1\n\t"
        "global_load_dwordx4 %3, %8, off offset:192 sc0 sc1\n\t"
        "global_load_dwordx4 %4, %8, off offset:256 sc0 sc1\n\t"
        "global_load_dwordx4 %5, %8, off offset:320 sc0 sc1\n\t"
        "global_load_dwordx4 %6, %8, off offset:384 sc0 sc1\n\t"
        "global_load_dwordx4 %7, %8, off offset:448 sc0 sc1\n\t"
        "s_waitcnt vmcnt(0)"
        : "=&v"(f[0]), "=&v"(f[1]), "=&v"(f[2]), "=&v"(f[3]),
          "=&v"(f[4]), "=&v"(f[5]), "=&v"(f[6]), "=&v"(f[7])
        : "v"(p)
        : "memory");
}
__device__ __forceinline__ void store_hb(unsigned short* p, unsigned short v) {
    unsigned int vv = v;
    asm volatile("global_store_short %0, %1, off sc0 sc1"
                 :: "v"(p), "v"(vv) : "memory");
}
__device__ __forceinline__ void vm_drain() {
    asm volatile("s_waitcnt vmcnt(0)" ::: "memory");
}

// Persistent LSTM: 256 blocks (1/CU) x 512 threads (8 waves).
// Block (bg,cg): bg = batch group (16 rows), cg = h-col group (16 cols x 4 gates).
// Waves 0-3 ("cell waves"): hold W_ih fragments, produce x-projection partials
//   for step t+1 OFF the critical path (double-buffered LDS, x prefetched one
//   step ahead into registers), and run the gate/cell epilogue.
// Waves 4-7 ("h waves"): hold W_hh fragments, own the critical path:
//   poll flags -> coherent h load -> MFMA -> LDS.
__global__ __launch_bounds__(512, 2) void lstm_persist(
    const float* __restrict__ x, const float* __restrict__ h0,
    const float* __restrict__ c0, const float* __restrict__ w_ih,
    const float* __restrict__ w_hh, const float* __restrict__ b_ih,
    const float* __restrict__ b_hh, float* __restrict__ out,
    unsigned short* __restrict__ hb, int* __restrict__ arrive)
{
    const int tid  = threadIdx.x;
    const int wave = tid >> 6;
    const int lane = tid & 63;
    const int bid  = blockIdx.x;
    const int bg   = bid >> 6;   // 0..3
    const int cg   = bid & 63;   // 0..63
    const int colbase = cg << 4;
    const int batbase = bg << 4;

    __shared__ float xred[2][4][4][4][64];  // [buf][wave][gate][reg][lane] 32 KB
    __shared__ float hred[4][4][4][64];     // [wave-4][gate][reg][lane]   16 KB

    const int quad = lane >> 4;
    const int l15  = lane & 15;

    // ---------- one-time weight preload into registers (bf16) ----------
    bf16x8 bw[8][4];
    {
        const float* wsrc = (wave < 4) ? w_ih : w_hh;
        const int koff = (wave & 3) * 256 + quad * 8;
        #pragma unroll
        for (int n = 0; n < 4; ++n) {
            const float* prow = wsrc + (size_t)((n << 10) + colbase + l15) * 1024 + koff;
            #pragma unroll
            for (int kk = 0; kk < 8; ++kk) {
                float4 a = *(const float4*)(prow + kk * 32);
                float4 b = *(const float4*)(prow + kk * 32 + 4);
                bw[kk][n] = cvt8(a, b);
            }
        }
    }

    // ---------- per-cell persistent state (threads 0..255 = waves 0-3) ----------
    float creg = 0.0f, bias0 = 0.f, bias1 = 0.f, bias2 = 0.f, bias3 = 0.f;
    int cellcolg = 0, cellb = 0;
    if (tid < 256) {
        const int cl = tid & 63;
        const int cv = tid >> 6;
        const int cellrow = ((cl >> 4) << 2) + cv;
        cellcolg = colbase + (cl & 15);
        cellb    = batbase + cellrow;
        creg  = c0[cellb * 1024 + cellcolg];
        bias0 = b_ih[cellcolg]        + b_hh[cellcolg];
        bias1 = b_ih[1024 + cellcolg] + b_hh[1024 + cellcolg];
        bias2 = b_ih[2048 + cellcolg] + b_hh[2048 + cellcolg];
        bias3 = b_ih[3072 + cellcolg] + b_hh[3072 + cellcolg];
    }

    float* outp = out;
    float* hnp  = out + (size_t)64 * 512 * 1024;
    float* cnp  = hnp + 64 * 1024;

    const int abatch = batbase + l15;   // A-operand row = batch

    // x prefetch registers (cell waves only; dead for h waves)
    float4 pa[8], pb[8];

    // ---------- preamble (cell waves): x-proj for t=0 into xred[0], prefetch t=1
    if (wave < 4) {
        const float* px = x + ((size_t)abatch * 512 + 0) * 1024 + wave * 256 + quad * 8;
        f32x4 xacc[4];
        #pragma unroll
        for (int n = 0; n < 4; ++n) xacc[n] = (f32x4){0.f, 0.f, 0.f, 0.f};
        #pragma unroll
        for (int kk = 0; kk < 8; ++kk) {
            float4 a = *(const float4*)(px + kk * 32);
            float4 b = *(const float4*)(px + kk * 32 + 4);
            bf16x8 af = cvt8(a, b);
            xacc[0] = __builtin_amdgcn_mfma_f32_16x16x32_bf16(af, bw[kk][0], xacc[0], 0, 0, 0);
            xacc[1] = __builtin_amdgcn_mfma_f32_16x16x32_bf16(af, bw[kk][1], xacc[1], 0, 0, 0);
            xacc[2] = __builtin_amdgcn_mfma_f32_16x16x32_bf16(af, bw[kk][2], xacc[2], 0, 0, 0);
            xacc[3] = __builtin_amdgcn_mfma_f32_16x16x32_bf16(af, bw[kk][3], xacc[3], 0, 0, 0);
        }
        #pragma unroll
        for (int n = 0; n < 4; ++n)
            #pragma unroll
            for (int v = 0; v < 4; ++v)
                xred[0][wave][n][v][lane] = xacc[n][v];
        const float* pn = x + ((size_t)abatch * 512 + 1) * 1024 + wave * 256 + quad * 8;
        #pragma unroll
        for (int kk = 0; kk < 8; ++kk) {
            pa[kk] = *(const float4*)(pn + kk * 32);
            pb[kk] = *(const float4*)(pn + kk * 32 + 4);
        }
    }

    for (int t = 0; t < T_STEPS; ++t) {
        // ---------- h waves: critical path ----------
        if (wave >= 4) {
            f32x4 acc[4];
            #pragma unroll
            for (int n = 0; n < 4; ++n) acc[n] = (f32x4){0.f, 0.f, 0.f, 0.f};

            if (t == 0) {
                const float* ph = h0 + abatch * 1024 + (wave & 3) * 256 + quad * 8;
                #pragma unroll
                for (int kk = 0; kk < 8; ++kk) {
                    float4 a = *(const float4*)(ph + kk * 32);
                    float4 b = *(const float4*)(ph + kk * 32 + 4);
                    bf16x8 af = cvt8(a, b);
                    acc[0] = __builtin_amdgcn_mfma_f32_16x16x32_bf16(af, bw[kk][0], acc[0], 0, 0, 0);
                    acc[1] = __builtin_amdgcn_mfma_f32_16x16x32_bf16(af, bw[kk][1], acc[1], 0, 0, 0);
                    acc[2] = __builtin_amdgcn_mfma_f32_16x16x32_bf16(af, bw[kk][2], acc[2], 0, 0, 0);
                    acc[3] = __builtin_amdgcn_mfma_f32_16x16x32_bf16(af, bw[kk][3], acc[3], 0, 0, 0);
                }
            } else {
                // poll: arrive[b] >= t  means h for step t-1 is visible
                const int* slot = &arrive[(bg << 6) + lane];
                while (__hip_atomic_load(slot, __ATOMIC_RELAXED,
                                         __HIP_MEMORY_SCOPE_AGENT) < t) {
                    __builtin_amdgcn_s_sleep(1);
                }
                const unsigned short* ph = hb + ((t - 1) & 1) * 65536
                                             + abatch * 1024 + (wave & 3) * 256 + quad * 8;
                uint4 fr[8];
                load_hb8(ph, fr);
                #pragma unroll
                for (int kk = 0; kk < 8; ++kk) {
                    union { uint4 u; bf16x8 v; } cc;
                    cc.u = fr[kk];
                    acc[0] = __builtin_amdgcn_mfma_f32_16x16x32_bf16(cc.v, bw[kk][0], acc[0], 0, 0, 0);
                    acc[1] = __builtin_amdgcn_mfma_f32_16x16x32_bf16(cc.v, bw[kk][1], acc[1], 0, 0, 0);
                    acc[2] = __builtin_amdgcn_mfma_f32_16x16x32_bf16(cc.v, bw[kk][2], acc[2], 0, 0, 0);
                    acc[3] = __builtin_amdgcn_mfma_f32_16x16x32_bf16(cc.v, bw[kk][3], acc[3], 0, 0, 0);
                }
            }
            #pragma unroll
            for (int n = 0; n < 4; ++n)
                #pragma unroll
                for (int v = 0; v < 4; ++v)
                    hred[wave - 4][n][v][lane] = acc[n][v];
        }

        __syncthreads();   // hred (and xred for t) ready

        float hval = 0.f;
        if (tid < 256) {
            const int cl = tid & 63;
            const int cv = tid >> 6;
            float g0 = bias0, g1 = bias1, g2 = bias2, g3 = bias3;
            #pragma unroll
            for (int w = 0; w < 4; ++w) {
                g0 += xred[t & 1][w][0][cv][cl] + hred[w][0][cv][cl];
                g1 += xred[t & 1][w][1][cv][cl] + hred[w][1][cv][cl];
                g2 += xred[t & 1][w][2][cv][cl] + hred[w][2][cv][cl];
                g3 += xred[t & 1][w][3][cv][cl] + hred[w][3][cv][cl];
            }
            float ig = fsig(g0), fg = fsig(g1), gg = ftanhf(g2), og = fsig(g3);
            creg = fg * creg + ig * gg;
            hval = og * ftanhf(creg);
            // coherent write-through of h for next step's consumers — FIRST
            store_hb(hb + (t & 1) * 65536 + cellb * 1024 + cellcolg, f2bfu(hval));
            vm_drain();
        }

        __syncthreads();   // all hb stores drained; hred consumed

        if (tid == 0 && t < T_STEPS - 1)
            __hip_atomic_store(&arrive[bid], t + 1, __ATOMIC_RELAXED,
                               __HIP_MEMORY_SCOPE_AGENT);
        // h waves loop straight back to polling for t+1.

        // ---------- cell waves: off-critical-path tail ----------
        if (wave < 4) {
            // fp32 h to outputs
            outp[((size_t)cellb * 512 + t) * 1024 + cellcolg] = hval;
            if (t == T_STEPS - 1) {
                hnp[cellb * 1024 + cellcolg] = hval;
                cnp[cellb * 1024 + cellcolg] = creg;
            }
            if (t < T_STEPS - 1) {
                // x-proj for t+1 from prefetched registers
                f32x4 xacc[4];
                #pragma unroll
                for (int n = 0; n < 4; ++n) xacc[n] = (f32x4){0.f, 0.f, 0.f, 0.f};
                #pragma unroll
                for (int kk = 0; kk < 8; ++kk) {
                    bf16x8 af = cvt8(pa[kk], pb[kk]);
                    xacc[0] = __builtin_amdgcn_mfma_f32_16x16x32_bf16(af, bw[kk][0], xacc[0], 0, 0, 0);
                    xacc[1] = __builtin_amdgcn_mfma_f32_16x16x32_bf16(af, bw[kk][1], xacc[1], 0, 0, 0);
                    xacc[2] = __builtin_amdgcn_mfma_f32_16x16x32_bf16(af, bw[kk][2], xacc[2], 0, 0, 0);
                    xacc[3] = __builtin_amdgcn_mfma_f32_16x16x32_bf16(af, bw[kk][3], xacc[3], 0, 0, 0);
                }
                #pragma unroll
                for (int n = 0; n < 4; ++n)
                    #pragma unroll
                    for (int v = 0; v < 4; ++v)
                        xred[(t + 1) & 1][wave][n][v][lane] = xacc[n][v];
                // prefetch x for t+2
                if (t + 2 < T_STEPS) {
                    const float* pn = x + ((size_t)abatch * 512 + (t + 2)) * 1024
                                        + wave * 256 + quad * 8;
                    #pragma unroll
                    for (int kk = 0; kk < 8; ++kk) {
                        pa[kk] = *(const float4*)(pn + kk * 32);
                        pb[kk] = *(const float4*)(pn + kk * 32 + 4);
                    }
                }
            }
        }
    }
}

extern "C" void kernel_launch(void* const* d_in, const int* in_sizes, int n_in,
                              void* d_out, int out_size, void* d_ws, size_t ws_size,
                              hipStream_t stream) {
    const float* x   = (const float*)d_in[0];
    const float* h0  = (const float*)d_in[1];
    const float* c0  = (const float*)d_in[2];
    const float* wih = (const float*)d_in[3];
    const float* whh = (const float*)d_in[4];
    const float* bih = (const float*)d_in[5];
    const float* bhh = (const float*)d_in[6];
    float* out = (float*)d_out;
    // ws layout: hb[2][64][1024] bf16 (256 KB) | arrive[256] int (1 KB)
    unsigned short* hb = (unsigned short*)d_ws;
    int* arrive = (int*)((char*)d_ws + 2 * 65536 * sizeof(unsigned short));
    hipLaunchKernelGGL(lstm_persist, dim3(256), dim3(512), 0, stream,
                       x, h0, c0, wih, whh, bih, bhh, out, hb, arrive);
}